// Round 6
// baseline (160.790 us; speedup 1.0000x reference)
//
#include <hip/hip_runtime.h>

// AdaptiveAngleConv round 6: persistent implicit-GEMM bf16 MFMA, pure-LDS K-loop,
// full-width tiles (2 rows x 128 w), nf=4 (6 LDS reads per 8 MFMA), raw lgkm-only
// barriers (stores drain under next K-loop), 2-batch T14 x-staging.
// 256 blocks x 512 thr (1/CU). Waves = (angle 0..3) x (row 0..1); wave M=64 x N=128.

#define CIN 64
#define COUT 64
#define HH 128
#define WW 128
#define NB 16
#define HW (HH*WW)

typedef short bf16x8 __attribute__((ext_vector_type(8)));
typedef float f32x16 __attribute__((ext_vector_type(16)));

// xs layout: byte(r, ci, wI) = XS_OFF + r*XS_ROW + (ci>>3)*XS_SLOT + wI*16 + (ci&7)*2
// wI = 0..129 maps x col -1..128 (wI 0 and 129 are permanently-zero halo).
// XS_SLOT = 2096 B (131 granules; 524 dw % 32 = 12 -> same conflict-free class as R5's 1072).
#define XS_SLOT 2096
#define XS_ROW  16768
#define XS_OFF  73728
#define LDS_BYTES (XS_OFF + 4 * XS_ROW)   // 140,800 B

// BOFF_d[a][s] = dh*XS_ROW + dw*16 for x-tap INV_a[s] paired with weight-tap s
// (R5-validated table rescaled 8576 -> 16768).
__device__ __constant__ unsigned BOFF_d[4][9] = {
  {0,16,32,16768,16784,16800,33536,33552,33568},
  {16,32,16800,0,16784,33568,16768,33536,33552},
  {32,16800,33568,16,16784,33552,0,16768,33536},
  {16800,33568,33552,32,16784,33536,16,0,16768},
};

static __device__ __forceinline__ unsigned short f2bf(float f) {
  unsigned u = __builtin_bit_cast(unsigned, f);
  return (unsigned short)((u + 0x7FFFu + ((u >> 16) & 1u)) >> 16);
}
static __device__ __forceinline__ unsigned pk2(float lo, float hi) {
  return (unsigned)f2bf(lo) | ((unsigned)f2bf(hi) << 16);
}

// Canonical A (R4/R5-validated): e = ((kc*2 + half)*64 + cm)*8 + j ; kc = s*4+q ;
// ci = q*16 + half*8 + j ; value = W[cm][ci][s]. 72 KB bf16.
__global__ void build_A_kernel(const float* __restrict__ wgt,
                               unsigned short* __restrict__ A) {
  const int e = blockIdx.x * 256 + threadIdx.x;
  const int j = e & 7;
  const int cm = (e >> 3) & 63;
  const int half = (e >> 9) & 1;
  const int kc = e >> 10;
  const int s = kc >> 2, q = kc & 3;
  const int ci = q * 16 + half * 8 + j;
  A[e] = f2bf(wgt[(cm * CIN + ci) * 9 + s]);
}

static __device__ __forceinline__ void lgkm_barrier() {
  asm volatile("s_waitcnt lgkmcnt(0)" ::: "memory");
  __builtin_amdgcn_s_barrier();
}

__global__ __launch_bounds__(512) void aconv_v6_kernel(
    const float* __restrict__ x,              // [B][CIN][H][W] fp32
    const unsigned short* __restrict__ Ag,    // canonical W, 36864 bf16
    const float* __restrict__ bias,           // [COUT]
    float* __restrict__ out)                  // [4][B][COUT][H][W] fp32
{
  __shared__ __align__(16) unsigned char lds[LDS_BYTES];

  const int tid = threadIdx.x;
  const int lane = tid & 63;
  const int wid = tid >> 6;
  const int a   = wid >> 1;         // angle
  const int row = wid & 1;          // output row within 2-row tile
  const int half = lane >> 5;
  const int ln = lane & 31;

  const int blk = blockIdx.x;       // 256 blocks = 16 b x 16 rem
  const int b   = blk >> 4;
  const int rem = blk & 15;
  const int hbase = rem * 8;

  unsigned boff[9];
  #pragma unroll
  for (int s = 0; s < 9; ++s) boff[s] = BOFF_d[a][s];

  // ---- stage canonical A (72 KB) into LDS ----
  {
    const uint4* Ag4 = (const uint4*)Ag;
    uint4* As4 = (uint4*)lds;
    #pragma unroll
    for (int i = 0; i < 9; ++i) As4[tid + i * 512] = Ag4[tid + i * 512];
  }
  // ---- zero the permanent w-halo granules (wI = 0 and 129) ----
  if (tid < 64) {
    const int r = tid >> 4, slot = (tid >> 1) & 7, wI = (tid & 1) * 129;
    uint4 z = {0u, 0u, 0u, 0u};
    *(uint4*)(lds + XS_OFF + r * XS_ROW + slot * XS_SLOT + wI * 16) = z;
  }

  // ---- per-thread staging geometry: granule i -> (r = i>>1, slot = (i&1)*4 + tid>>7,
  //      wI = 1 + (tid&127)); 8 granules x 512 threads = 4096 = 4 rows x 8 slots x 128 ----
  const int sslot = tid >> 7;
  const int scol  = tid & 127;
  const float* xb[2];
  xb[0] = x + (size_t)(b * CIN + sslot * 8) * HW + scol;
  xb[1] = x + (size_t)(b * CIN + (4 + sslot) * 8) * HW + scol;
  unsigned sdst[8];
  #pragma unroll
  for (int i = 0; i < 8; ++i)
    sdst[i] = (unsigned)(XS_OFF + (i >> 1) * XS_ROW + ((i & 1) * 4 + sslot) * XS_SLOT
                         + (1 + scol) * 16);

  // ---- prologue: stage tile 0 (h0 = hbase) ----
  {
    float gv[8][8];
    #pragma unroll
    for (int i = 0; i < 8; ++i) {
      const int gh = hbase - 1 + (i >> 1);
      const bool inb = (unsigned)gh < HH;
      const float* xp = xb[i & 1] + (size_t)gh * WW;
      #pragma unroll
      for (int q = 0; q < 8; ++q) gv[i][q] = inb ? xp[(size_t)q * HW] : 0.f;
    }
    #pragma unroll
    for (int i = 0; i < 8; ++i) {
      uint4 u;
      u.x = pk2(gv[i][0], gv[i][1]); u.y = pk2(gv[i][2], gv[i][3]);
      u.z = pk2(gv[i][4], gv[i][5]); u.w = pk2(gv[i][6], gv[i][7]);
      *(uint4*)(lds + sdst[i]) = u;
    }
  }
  __syncthreads();

  const unsigned char* Asb = lds + (unsigned)(half * 1024 + ln * 16);
  const unsigned char* Bsb = lds + XS_OFF + (unsigned)(row * XS_ROW + half * XS_SLOT + ln * 16);

  #pragma unroll 1
  for (int it = 0; it < 4; ++it) {
    const int h0 = hbase + it * 2;
    const bool pf = (it < 3);

    f32x16 acc[2][4];
    #pragma unroll
    for (int mf = 0; mf < 2; ++mf)
      #pragma unroll
      for (int wq = 0; wq < 4; ++wq) acc[mf][wq] = (f32x16)(0.f);

    auto kstep = [&](int kc) {
      const int s = kc >> 2, q = kc & 3;
      const bf16x8 af0 = *(const bf16x8*)(Asb + kc * 2048);
      const bf16x8 af1 = *(const bf16x8*)(Asb + kc * 2048 + 512);
      const unsigned bb = boff[s] + (unsigned)(q * 2 * XS_SLOT);
      bf16x8 bfv[4];
      #pragma unroll
      for (int wq = 0; wq < 4; ++wq)
        bfv[wq] = *(const bf16x8*)(Bsb + bb + wq * 512);
      #pragma unroll
      for (int wq = 0; wq < 4; ++wq) {
        acc[0][wq] = __builtin_amdgcn_mfma_f32_32x32x16_bf16(af0, bfv[wq], acc[0][wq], 0, 0, 0);
        acc[1][wq] = __builtin_amdgcn_mfma_f32_32x32x16_bf16(af1, bfv[wq], acc[1][wq], 0, 0, 0);
      }
    };

    // issue batch A of next tile's x (rows r=0,1) -- lands during K first half
    float gA[4][8];
    if (pf) {
      #pragma unroll
      for (int i = 0; i < 4; ++i) {
        const int gh = h0 + 1 + (i >> 1);
        const bool inb = (unsigned)gh < HH;
        const float* xp = xb[i & 1] + (size_t)gh * WW;
        #pragma unroll
        for (int q = 0; q < 8; ++q) gA[i][q] = inb ? xp[(size_t)q * HW] : 0.f;
      }
    }

    #pragma unroll
    for (int kc = 0; kc < 18; ++kc) kstep(kc);

    // pack batch A (loads long landed), issue batch B (rows r=2,3)
    uint4 gpA[4];
    float gB[4][8];
    if (pf) {
      #pragma unroll
      for (int i = 0; i < 4; ++i) {
        gpA[i].x = pk2(gA[i][0], gA[i][1]); gpA[i].y = pk2(gA[i][2], gA[i][3]);
        gpA[i].z = pk2(gA[i][4], gA[i][5]); gpA[i].w = pk2(gA[i][6], gA[i][7]);
      }
      #pragma unroll
      for (int i = 0; i < 4; ++i) {
        const int gh = h0 + 3 + (i >> 1);
        const bool inb = (unsigned)gh < HH;
        const float* xp = xb[i & 1] + (size_t)gh * WW;
        #pragma unroll
        for (int q = 0; q < 8; ++q) gB[i][q] = inb ? xp[(size_t)q * HW] : 0.f;
      }
    }

    #pragma unroll
    for (int kc = 18; kc < 36; ++kc) kstep(kc);

    uint4 gpB[4];
    if (pf) {
      #pragma unroll
      for (int i = 0; i < 4; ++i) {
        gpB[i].x = pk2(gB[i][0], gB[i][1]); gpB[i].y = pk2(gB[i][2], gB[i][3]);
        gpB[i].z = pk2(gB[i][4], gB[i][5]); gpB[i].w = pk2(gB[i][6], gB[i][7]);
      }
    }

    // epilogue: bias (L1-hot loads) + stores; stores drain under next K-loop
    #pragma unroll
    for (int mf = 0; mf < 2; ++mf) {
      const int cob = mf * 32 + 4 * half;
      float bvl[16];
      #pragma unroll
      for (int g = 0; g < 16; ++g)
        bvl[g] = bias[cob + (g & 3) + 8 * (g >> 2)];
      #pragma unroll
      for (int wq = 0; wq < 4; ++wq) {
        const f32x16 v = acc[mf][wq];
        float* op = out + (((size_t)(a * NB + b) * COUT + cob) * HH + (h0 + row)) * WW
                    + wq * 32 + ln;
        #pragma unroll
        for (int g = 0; g < 16; ++g)
          op[(size_t)((g & 3) + 8 * (g >> 2)) * HW] = v[g] + bvl[g];
      }
    }

    lgkm_barrier();                 // all waves done reading xs (lgkm only -- no store drain)
    if (pf) {
      #pragma unroll
      for (int i = 0; i < 4; ++i) *(uint4*)(lds + sdst[i]) = gpA[i];
      #pragma unroll
      for (int i = 0; i < 4; ++i) *(uint4*)(lds + sdst[4 + i]) = gpB[i];
    }
    lgkm_barrier();                 // xs ready for next tile
  }
}

extern "C" void kernel_launch(void* const* d_in, const int* in_sizes, int n_in,
                              void* d_out, int out_size, void* d_ws, size_t ws_size,
                              hipStream_t stream) {
  const float* x    = (const float*)d_in[0];
  const float* wgt  = (const float*)d_in[1];
  const float* bias = (const float*)d_in[2];
  float* out = (float*)d_out;
  unsigned short* A = (unsigned short*)d_ws;   // 73,728 B

  build_A_kernel<<<144, 256, 0, stream>>>(wgt, A);
  aconv_v6_kernel<<<256, 512, 0, stream>>>(x, A, bias, out);
}

// Round 7
// 101.309 us; speedup vs baseline: 1.5871x; 1.5871x over previous
//
#include <hip/hip_runtime.h>

// AdaptiveAngleConv round 7: R5 persistent structure (acc 64 AGPR, pure-LDS K-loop)
// + lgkm-only barriers (stores drain under next K-loop)
// + rolling 2-row x staging (w-half outer, h inner)  + cross-half prologue prefetch
// + nontemporal out stores.
// 256 blocks x 512 thr (1/CU). Waves = (angle 0..3) x (row 0..1); wave M=64 x N=64.

#define CIN 64
#define COUT 64
#define HH 128
#define WW 128
#define NB 16
#define HW (HH*WW)

typedef short bf16x8 __attribute__((ext_vector_type(8)));
typedef float f32x16 __attribute__((ext_vector_type(16)));

// xs layout (R5-proven, 0 conflicts): byte(slot_row, ci, wI) =
//   XS_OFF + slot_row*XS_ROW + (ci>>3)*XS_SLOT + wI*16 + (ci&7)*2 ; wI 0..65 = w0-1..w0+64
#define XS_SLOT 1072
#define XS_ROW  8576
#define XS_OFF  73728
#define LDS_BYTES (XS_OFF + 4 * XS_ROW)   // 108,032 B

// Per weight-tap s, the paired x-tap t = INV_a[s]; split into dh index and dw bytes.
__device__ __constant__ unsigned char DHI_d[4][9] = {
  {0,0,0,1,1,1,2,2,2},
  {0,0,1,0,1,2,1,2,2},
  {0,1,2,0,1,2,0,1,2},
  {1,2,2,0,1,2,0,0,1},
};
__device__ __constant__ unsigned short DWB_d[4][9] = {   // (t%3)*16
  {0,16,32,0,16,32,0,16,32},
  {16,32,32,0,16,32,0,0,16},
  {32,32,32,16,16,16,0,0,0},
  {32,32,16,32,16,0,16,0,0},
};

static __device__ __forceinline__ unsigned short f2bf(float f) {
  unsigned u = __builtin_bit_cast(unsigned, f);
  return (unsigned short)((u + 0x7FFFu + ((u >> 16) & 1u)) >> 16);
}
static __device__ __forceinline__ unsigned pk2(float lo, float hi) {
  return (unsigned)f2bf(lo) | ((unsigned)f2bf(hi) << 16);
}

// Canonical A (R4/R5-validated): e = ((kc*2 + half)*64 + cm)*8 + j ; kc = s*4+q ;
// ci = q*16 + half*8 + j ; value = W[cm][ci][s]. 72 KB bf16.
__global__ void build_A_kernel(const float* __restrict__ wgt,
                               unsigned short* __restrict__ A) {
  const int e = blockIdx.x * 256 + threadIdx.x;
  const int j = e & 7;
  const int cm = (e >> 3) & 63;
  const int half = (e >> 9) & 1;
  const int kc = e >> 10;
  const int s = kc >> 2, q = kc & 3;
  const int ci = q * 16 + half * 8 + j;
  A[e] = f2bf(wgt[(cm * CIN + ci) * 9 + s]);
}

static __device__ __forceinline__ void lgkm_barrier() {
  asm volatile("s_waitcnt lgkmcnt(0)" ::: "memory");
  __builtin_amdgcn_s_barrier();
}

__global__ __launch_bounds__(512) void aconv_v7_kernel(
    const float* __restrict__ x,              // [B][CIN][H][W] fp32
    const unsigned short* __restrict__ Ag,    // canonical W, 36864 bf16
    const float* __restrict__ bias,           // [COUT]
    float* __restrict__ out)                  // [4][B][COUT][H][W] fp32
{
  __shared__ __align__(16) unsigned char lds[LDS_BYTES];

  const int tid = threadIdx.x;
  const int lane = tid & 63;
  const int wid = tid >> 6;
  const int a   = wid >> 1;         // angle
  const int row = wid & 1;          // output row within 2-row tile
  const int half = lane >> 5;
  const int ln = lane & 31;

  const int blk = blockIdx.x;       // 256 blocks = 16 b x 16 rem
  const int b   = blk >> 4;
  const int rem = blk & 15;
  const int hbase = rem * 8;

  // bias fragments (co = mf*32 + (g&3)+8*(g>>2)+4*half)
  float bv[2][16];
  #pragma unroll
  for (int mf = 0; mf < 2; ++mf)
    #pragma unroll
    for (int g = 0; g < 16; ++g)
      bv[mf][g] = bias[mf * 32 + (g & 3) + 8 * (g >> 2) + 4 * half];

  int dhi[9]; unsigned dwb[9];
  #pragma unroll
  for (int s = 0; s < 9; ++s) { dhi[s] = DHI_d[a][s]; dwb[s] = DWB_d[a][s]; }

  // ---- stage canonical A (72 KB) ----
  {
    const uint4* Ag4 = (const uint4*)Ag;
    uint4* As4 = (uint4*)lds;
    #pragma unroll
    for (int i = 0; i < 9; ++i) As4[tid + i * 512] = Ag4[tid + i * 512];
  }

  float gv[5][8];
  unsigned gdst[5];
  bool gval[5];

  // ---- initial prologue: rows hbase-1..hbase+2 (slots 0..3), w-half 0 ----
  #pragma unroll
  for (int i = 0; i < 5; ++i) {
    const int g = tid + i * 512;
    const bool v = g < 2112;
    const int rg = g / 528;
    const int rest = g - rg * 528;
    const int slot = rest / 66;
    const int wI = rest - slot * 66;
    const int hx = hbase - 1 + rg;
    const int gw = -1 + wI;
    const bool inb = v && ((unsigned)hx < HH) && ((unsigned)gw < WW);
    const float* xp = x + (size_t)(b * CIN + slot * 8) * HW + (size_t)hx * WW + gw;
    gval[i] = v;
    gdst[i] = (unsigned)(XS_OFF + rg * XS_ROW + slot * XS_SLOT + wI * 16);
    #pragma unroll
    for (int q = 0; q < 8; ++q) gv[i][q] = inb ? xp[(size_t)q * HW] : 0.f;
  }
  #pragma unroll
  for (int i = 0; i < 5; ++i)
    if (gval[i]) {
      uint4 u;
      u.x = pk2(gv[i][0], gv[i][1]); u.y = pk2(gv[i][2], gv[i][3]);
      u.z = pk2(gv[i][4], gv[i][5]); u.w = pk2(gv[i][6], gv[i][7]);
      *(uint4*)(lds + gdst[i]) = u;
    }
  __syncthreads();

  const unsigned char* Asb = lds + (unsigned)(half * 1024 + ln * 16);
  const unsigned char* Bsb = lds + XS_OFF + (unsigned)(half * XS_SLOT + ln * 16);

  #pragma unroll 1
  for (int ti = 0; ti < 8; ++ti) {
    const int wh = ti >> 2, it = ti & 3;
    const int w0 = wh * 64;

    // per-tile B offsets: rolling slot = (2*it + row + dh) & 3
    unsigned boff_t[9];
    {
      unsigned rowoff[3];
      #pragma unroll
      for (int dh = 0; dh < 3; ++dh)
        rowoff[dh] = (unsigned)(((2 * it + row + dh) & 3) * XS_ROW);
      #pragma unroll
      for (int s = 0; s < 9; ++s) boff_t[s] = dwb[s] + rowoff[dhi[s]];
    }

    // ---- issue prefetch loads (consumed after barrier -> latency hidden) ----
    const bool pf2 = (it < 3);                 // 2 new rows, same w-half
    const bool pf4 = (it == 3) && (wh == 0);   // 4-row prologue of w-half 1
    const int ngran = pf2 ? 1056 : (pf4 ? 2112 : 0);
    if (ngran) {
      const int itv = pf4 ? -2 : it;           // unifies: hx = hbase+2*itv+3+rg
      const int w0n = pf4 ? 64 : w0;
      #pragma unroll
      for (int i = 0; i < 5; ++i) {
        const int g = tid + i * 512;
        const bool v = g < ngran;
        const int rg = g / 528;
        const int rest = g - rg * 528;
        const int slot = rest / 66;
        const int wI = rest - slot * 66;
        const int hx = hbase + 2 * itv + 3 + rg;
        const int ps = (2 * itv + 4 + rg) & 3;
        const int gw = w0n - 1 + wI;
        const bool inb = v && ((unsigned)hx < HH) && ((unsigned)gw < WW);
        const float* xp = x + (size_t)(b * CIN + slot * 8) * HW + (size_t)hx * WW + gw;
        gval[i] = v;
        gdst[i] = (unsigned)(XS_OFF + ps * XS_ROW + slot * XS_SLOT + wI * 16);
        #pragma unroll
        for (int q = 0; q < 8; ++q) gv[i][q] = inb ? xp[(size_t)q * HW] : 0.f;
      }
    }

    // ---- acc init with bias; pure-LDS K-loop: 36 steps of K=16 ----
    f32x16 acc[2][2];
    #pragma unroll
    for (int mf = 0; mf < 2; ++mf)
      #pragma unroll
      for (int nf = 0; nf < 2; ++nf)
        #pragma unroll
        for (int g = 0; g < 16; ++g)
          acc[mf][nf][g] = bv[mf][g];

    #pragma unroll
    for (int kc = 0; kc < 36; ++kc) {
      const bf16x8 af0 = *(const bf16x8*)(Asb + kc * 2048);
      const bf16x8 af1 = *(const bf16x8*)(Asb + kc * 2048 + 512);
      const unsigned bb = boff_t[kc >> 2] + (unsigned)((kc & 3) * 2 * XS_SLOT);
      const bf16x8 bf0 = *(const bf16x8*)(Bsb + bb);
      const bf16x8 bf1 = *(const bf16x8*)(Bsb + bb + 512);
      acc[0][0] = __builtin_amdgcn_mfma_f32_32x32x16_bf16(af0, bf0, acc[0][0], 0, 0, 0);
      acc[0][1] = __builtin_amdgcn_mfma_f32_32x32x16_bf16(af0, bf1, acc[0][1], 0, 0, 0);
      acc[1][0] = __builtin_amdgcn_mfma_f32_32x32x16_bf16(af1, bf0, acc[1][0], 0, 0, 0);
      acc[1][1] = __builtin_amdgcn_mfma_f32_32x32x16_bf16(af1, bf1, acc[1][1], 0, 0, 0);
    }

    // ---- nontemporal stores (drain under next K-loop; bias already in acc) ----
    const int hout = hbase + it * 2 + row;
    #pragma unroll
    for (int mf = 0; mf < 2; ++mf)
      #pragma unroll
      for (int nf = 0; nf < 2; ++nf) {
        const f32x16 v = acc[mf][nf];
        float* op = out + (((size_t)(a * NB + b) * COUT + mf * 32 + 4 * half) * HH
                           + hout) * WW + w0 + nf * 32 + ln;
        #pragma unroll
        for (int g = 0; g < 16; ++g)
          __builtin_nontemporal_store(v[g], op + (size_t)((g & 3) + 8 * (g >> 2)) * HW);
      }

    lgkm_barrier();                 // all waves' ds_reads of xs complete (lgkm only)
    if (ngran) {
      #pragma unroll
      for (int i = 0; i < 5; ++i)
        if (gval[i]) {
          uint4 u;
          u.x = pk2(gv[i][0], gv[i][1]); u.y = pk2(gv[i][2], gv[i][3]);
          u.z = pk2(gv[i][4], gv[i][5]); u.w = pk2(gv[i][6], gv[i][7]);
          *(uint4*)(lds + gdst[i]) = u;
        }
    }
    lgkm_barrier();                 // new rows visible for next tile
  }
}

extern "C" void kernel_launch(void* const* d_in, const int* in_sizes, int n_in,
                              void* d_out, int out_size, void* d_ws, size_t ws_size,
                              hipStream_t stream) {
  const float* x    = (const float*)d_in[0];
  const float* wgt  = (const float*)d_in[1];
  const float* bias = (const float*)d_in[2];
  float* out = (float*)d_out;
  unsigned short* A = (unsigned short*)d_ws;   // 73,728 B

  build_A_kernel<<<144, 256, 0, stream>>>(wgt, A);
  aconv_v7_kernel<<<256, 512, 0, stream>>>(x, A, bias, out);
}